// Round 8
// baseline (342.947 us; speedup 1.0000x reference)
//
#include <hip/hip_runtime.h>
#include <hip/hip_fp16.h>

#define NNODES 100000
#define NEDGES 3200000
#define FEAT 32
#define NITER 5
#define NF (NNODES * FEAT)

#define EDGE_BLOCKS (NEDGES / 256)     // 12500, exact

// bucket partition
#define BUCK_SH 7
#define BUCK_SZ 128                    // dsts per bucket
#define NBK 782                        // ceil(100000/128)
#define CHUNKF 8192                    // edges per fill block
#define NBF 391                        // ceil(3.2M/8192): 391*8192 = 3,203,072
#define NT (NBF * NBK)                 // 305,762 matrix elements
#define NTB 299                        // ceil(NT/1024)

// ---- pass A: per-edge weight + masked dst array + masked-weight partials ----
__global__ void ws_kernel(const int* __restrict__ edge_index,
                          const int* __restrict__ edge_mask,
                          const float* __restrict__ edge_scale,
                          const float* __restrict__ pert_mask,
                          const float* __restrict__ edge_weight,
                          int* __restrict__ dstm,
                          int* __restrict__ wbuf,
                          float* __restrict__ S_part) {
    const int e = blockIdx.x * 256 + threadIdx.x;   // grid covers NEDGES exactly
    const int m = edge_mask[e];
    const float w = (edge_weight[e] * (1.0f - pert_mask[e]) + pert_mask[e]) * edge_scale[e];
    wbuf[e] = __float_as_int(w);
    dstm[e] = m ? edge_index[NEDGES + e] : -1;
    float ms = m ? 0.0f : w;
    __shared__ float s[256];
    s[threadIdx.x] = ms;
    __syncthreads();
    for (int off = 128; off; off >>= 1) {
        if (threadIdx.x < off) s[threadIdx.x] += s[threadIdx.x + off];
        __syncthreads();
    }
    if (threadIdx.x == 0) S_part[blockIdx.x] = s[0];
}

__global__ void sreduce_kernel(const float* __restrict__ S_part, float* __restrict__ S) {
    __shared__ float s[1024];
    float a = 0.0f;
    for (int i = threadIdx.x; i < EDGE_BLOCKS; i += 1024) a += S_part[i];
    s[threadIdx.x] = a;
    __syncthreads();
    for (int off = 512; off; off >>= 1) {
        if (threadIdx.x < off) s[threadIdx.x] += s[threadIdx.x + off];
        __syncthreads();
    }
    if (threadIdx.x == 0) *S = s[0];
}

// ---- per-(block,bucket) histogram matrix: M[b*NBK + k] ----
__global__ void histmat_kernel(const int* __restrict__ dstm, int* __restrict__ M) {
    __shared__ int h[NBK];
    const int b = blockIdx.x;
    for (int k = threadIdx.x; k < NBK; k += 256) h[k] = 0;
    __syncthreads();
    const int base = b * CHUNKF;
    #pragma unroll
    for (int it = 0; it < CHUNKF / 256; ++it) {
        const int e = base + it * 256 + threadIdx.x;
        if (e < NEDGES) {
            const int d = dstm[e];
            if (d >= 0) atomicAdd(&h[d >> BUCK_SH], 1);
        }
    }
    __syncthreads();
    for (int k = threadIdx.x; k < NBK; k += 256) M[b * NBK + k] = h[k];
}

// ---- 3-stage exclusive scan over M in bucket-major (transposed) order ----
__global__ void tscan1_kernel(const int* __restrict__ M, int* __restrict__ tb) {
    __shared__ int s[1024];
    const int i = blockIdx.x * 1024 + threadIdx.x;
    int v = 0;
    if (i < NT) v = M[(i % NBF) * NBK + (i / NBF)];
    s[threadIdx.x] = v;
    __syncthreads();
    for (int off = 512; off; off >>= 1) {
        if (threadIdx.x < off) s[threadIdx.x] += s[threadIdx.x + off];
        __syncthreads();
    }
    if (threadIdx.x == 0) tb[blockIdx.x] = s[0];
}

__global__ void tscan2_kernel(const int* __restrict__ tb, int* __restrict__ tboff,
                              int* __restrict__ bucket_base) {
    __shared__ int s[512];
    const int tid = threadIdx.x;
    int v = (tid < NTB) ? tb[tid] : 0;
    s[tid] = v;
    __syncthreads();
    for (int off = 1; off < 512; off <<= 1) {
        int t = (tid >= off) ? s[tid - off] : 0;
        __syncthreads();
        s[tid] += t;
        __syncthreads();
    }
    if (tid < NTB) tboff[tid] = s[tid] - v;     // exclusive
    if (tid == 511) bucket_base[NBK] = s[511];  // total unmasked edges
}

__global__ void tscan3_kernel(const int* __restrict__ M, const int* __restrict__ tboff,
                              int* __restrict__ scanT, int* __restrict__ bucket_base) {
    __shared__ int s[1024];
    const int tid = threadIdx.x;
    const int i = blockIdx.x * 1024 + tid;
    int v = 0;
    if (i < NT) v = M[(i % NBF) * NBK + (i / NBF)];
    s[tid] = v;
    __syncthreads();
    for (int off = 1; off < 1024; off <<= 1) {
        int t = (tid >= off) ? s[tid - off] : 0;
        __syncthreads();
        s[tid] += t;
        __syncthreads();
    }
    if (i < NT) {
        const int excl = tboff[blockIdx.x] + s[tid] - v;
        scanT[i] = excl;
        if (i % NBF == 0) bucket_base[i / NBF] = excl;
    }
}

// ---- fill: scatter (src | dstl<<20, w) to matrix offsets; no global atomics ----
__global__ void fill782_kernel(const int* __restrict__ edge_index,
                               const int* __restrict__ dstm,
                               const int* __restrict__ wbuf,
                               const int* __restrict__ scanT,
                               int2* __restrict__ e8tmp) {
    __shared__ int off[NBK];
    const int b = blockIdx.x;
    for (int k = threadIdx.x; k < NBK; k += 256) off[k] = scanT[k * NBF + b];
    __syncthreads();
    const int base = b * CHUNKF;
    #pragma unroll
    for (int it = 0; it < CHUNKF / 256; ++it) {
        const int e = base + it * 256 + threadIdx.x;
        if (e < NEDGES) {
            const int d = dstm[e];
            if (d >= 0) {
                const int k = d >> BUCK_SH;
                const int dstl = d & (BUCK_SZ - 1);
                const int pos = atomicAdd(&off[k], 1);
                e8tmp[pos] = make_int2(edge_index[e] | (dstl << 20), wbuf[e]);
            }
        }
    }
}

// ---- bucket sort: one block per bucket; LDS counting sort by local dst ----
// emits final dst-sorted e8 (x = fp16-row byte offset, src<<6) and row_ptr
__global__ void bsort_kernel(const int2* __restrict__ e8tmp,
                             const int* __restrict__ bucket_base,
                             int2* __restrict__ e8,
                             int* __restrict__ row_ptr) {
    __shared__ int h[BUCK_SZ];
    __shared__ int s[BUCK_SZ];
    __shared__ int woff[BUCK_SZ];
    const int k = blockIdx.x;
    const int tid = threadIdx.x;
    const int base0 = bucket_base[k];
    const int cnt = bucket_base[k + 1] - base0;
    if (tid < BUCK_SZ) h[tid] = 0;
    __syncthreads();
    for (int i = tid; i < cnt; i += 256) {
        const int dstl = e8tmp[base0 + i].x >> 20;
        atomicAdd(&h[dstl], 1);
    }
    __syncthreads();
    if (tid < BUCK_SZ) s[tid] = h[tid];
    __syncthreads();
    for (int off = 1; off < BUCK_SZ; off <<= 1) {
        int t = 0;
        if (tid < BUCK_SZ && tid >= off) t = s[tid - off];
        __syncthreads();
        if (tid < BUCK_SZ) s[tid] += t;
        __syncthreads();
    }
    if (tid < BUCK_SZ) {
        const int excl = s[tid] - h[tid];
        const int d = k * BUCK_SZ + tid;
        if (d < NNODES) row_ptr[d] = base0 + excl;
        woff[tid] = excl;
    }
    if (k == NBK - 1 && tid == 0) row_ptr[NNODES] = bucket_base[NBK];
    __syncthreads();
    for (int i = tid; i < cnt; i += 256) {
        const int2 v = e8tmp[base0 + i];
        const int dstl = v.x >> 20;
        const int src = v.x & 0xFFFFF;
        const int pos = atomicAdd(&woff[dstl], 1);
        e8[base0 + pos] = make_int2(src << 6, v.y);   // byte offset into fp16 rows (64 B)
    }
}

// ---- initial fp32 -> fp16 conversion of x0 ----
__global__ void cvt_kernel(const float* __restrict__ x, __half* __restrict__ xh) {
    const int i = blockIdx.x * 256 + threadIdx.x;   // i over NF/4
    const float4 v = reinterpret_cast<const float4*>(x)[i];
    __half2* o = reinterpret_cast<__half2*>(xh) + i * 2;
    o[0] = __floats2half2_rn(v.x, v.y);
    o[1] = __floats2half2_rn(v.z, v.w);
}

// ---- gather + fused hardtanh update: 64 lanes (1 wave) per node ----
// neighbor operand read from fp16 copy (64 B rows = 1 line/edge); self term fp32.
__global__ void gather_kernel(const float* __restrict__ x,
                              const __half* __restrict__ xh,
                              const int* __restrict__ row_ptr,
                              const int2* __restrict__ e8,
                              const float* __restrict__ S,
                              float* __restrict__ out,
                              __half* __restrict__ outh) {
    const int gid = blockIdx.x * blockDim.x + threadIdx.x;
    const int node = gid >> 6;
    const int lane = threadIdx.x & 63;
    const int f = lane & 31;
    const int h = lane >> 5;
    if (node >= NNODES) return;
    const int beg = row_ptr[node];
    const int end = row_ptr[node + 1];
    const char* xhc = (const char*)xh;
    const int f2 = f << 1;
    const float xi = x[node * FEAT + f];

    float a0 = 0.0f, a1 = 0.0f;
    int e = beg + (h << 3);
    // fast path: full 8-entry chunks
    for (; e + 8 <= end; e += 16) {
        int2 s[8];
        #pragma unroll
        for (int k = 0; k < 8; ++k) s[k] = e8[e + k];
        #pragma unroll
        for (int k = 0; k < 8; ++k) {
            const float v = __half2float(*(const __half*)(xhc + (s[k].x + f2)));
            if (k & 1) a1 = fmaf(__int_as_float(s[k].y), v, a1);
            else       a0 = fmaf(__int_as_float(s[k].y), v, a0);
        }
    }
    // tail: at most one clamped chunk per half
    if (e < end) {
        const int em1 = end - 1;
        int2 s[8];
        #pragma unroll
        for (int k = 0; k < 8; ++k) s[k] = e8[min(e + k, em1)];
        #pragma unroll
        for (int k = 0; k < 8; ++k) {
            const float v = __half2float(*(const __half*)(xhc + (s[k].x + f2)));
            const float w = (e + k < end) ? __int_as_float(s[k].y) : 0.0f;
            if (k & 1) a1 = fmaf(w, v, a1);
            else       a0 = fmaf(w, v, a0);
        }
    }
    float acc = a0 + a1;
    acc += __shfl_xor(acc, 32);          // combine the two halves
    if (node == 0) acc += S[0] * x[f];   // masked-edge bulk contribution (fp32)
    const float d = fminf(fmaxf(acc - xi, -1.0f), 1.0f);
    const float r = fminf(fmaxf(xi + d, 0.0f), 2.0f);
    if (h == 0) {
        out[node * FEAT + f] = r;
        outh[node * FEAT + f] = __float2half_rn(r);
    }
}

extern "C" void kernel_launch(void* const* d_in, const int* in_sizes, int n_in,
                              void* d_out, int out_size, void* d_ws, size_t ws_size,
                              hipStream_t stream) {
    const float* x0         = (const float*)d_in[0];
    const int*   edge_index = (const int*)d_in[1];
    const int*   edge_mask  = (const int*)d_in[2];
    const float* edge_scale = (const float*)d_in[3];
    const float* pert_mask  = (const float*)d_in[4];
    const float* edge_weight= (const float*)d_in[5];
    float* xout = (float*)d_out;

    // ---- workspace layout ----
    // [0, 80K)       scalars / scan temporaries
    // [80K, 512K)    row_ptr
    // [512K, 2M)     M ; [2M, 4M) scanT
    // [4M, 16.8M)    x_mid (fp32, live all gathers)
    // [17M, 29.8M)   e8tmp (dead after bsort)
    // [30M, 42.8M)   e8 (live all gathers)
    // [43M, 49.4M)   xh0 ; [50M, 56.4M) xh1   -- reuse wbuf/dstm region (dead after fill782)
    char* ws = (char*)d_ws;
    float* S        = (float*)(ws);                          // 4 B
    float* S_part   = (float*)(ws + 1024);                   // 12500 floats
    int*   tb       = (int*)(ws + 64 * 1024);                // 299 ints
    int*   tboff    = (int*)(ws + 68 * 1024);                // 299 ints
    int*   bbase    = (int*)(ws + 72 * 1024);                // 783 ints
    int*   row_ptr  = (int*)(ws + 80 * 1024);                // 100001 ints
    int*   M        = (int*)(ws + 512 * 1024);               // NT ints (1.22 MB)
    int*   scanT    = (int*)(ws + 2  * 1024 * 1024);         // NT ints (1.22 MB)
    float* x_mid    = (float*)(ws + 4  * 1024 * 1024);       // 12.8 MB
    int2*  e8tmp    = (int2*)(ws + 17 * 1024 * 1024);        // 12.8 MB (dead after bsort)
    int2*  e8       = (int2*)(ws + 30 * 1024 * 1024);        // 12.8 MB
    int*   wbuf     = (int*)(ws + 43 * 1024 * 1024);         // 12.8 MB (dead after fill782)
    int*   dstm     = (int*)(ws + 56 * 1024 * 1024);         // 12.8 MB (dead after fill782)
    __half* xh0     = (__half*)(ws + 43 * 1024 * 1024);      // 6.4 MB, aliases dead wbuf
    __half* xh1     = (__half*)(ws + 50 * 1024 * 1024);      // 6.4 MB, aliases dead wbuf/dstm

    ws_kernel<<<EDGE_BLOCKS, 256, 0, stream>>>(edge_index, edge_mask, edge_scale,
                                               pert_mask, edge_weight, dstm, wbuf, S_part);
    sreduce_kernel<<<1, 1024, 0, stream>>>(S_part, S);
    histmat_kernel<<<NBF, 256, 0, stream>>>(dstm, M);
    tscan1_kernel<<<NTB, 1024, 0, stream>>>(M, tb);
    tscan2_kernel<<<1, 512, 0, stream>>>(tb, tboff, bbase);
    tscan3_kernel<<<NTB, 1024, 0, stream>>>(M, tboff, scanT, bbase);
    fill782_kernel<<<NBF, 256, 0, stream>>>(edge_index, dstm, wbuf, scanT, e8tmp);
    bsort_kernel<<<NBK, 256, 0, stream>>>(e8tmp, bbase, e8, row_ptr);
    cvt_kernel<<<NF / 4 / 256, 256, 0, stream>>>(x0, xh0);   // 3125 blocks, exact

    // 5 gather iterations, ping-pong: x0 -> out -> mid -> out -> mid -> out
    const int gblocks = (NNODES * 64) / 256;   // 25000, exact
    const float* cur = x0;
    float* bufs[NITER] = { xout, x_mid, xout, x_mid, xout };
    __half* xhb[2] = { xh0, xh1 };
    for (int it = 0; it < NITER; ++it) {
        gather_kernel<<<gblocks, 256, 0, stream>>>(cur, xhb[it & 1], row_ptr, e8, S,
                                                   bufs[it], xhb[(it + 1) & 1]);
        cur = bufs[it];
    }
}

// Round 9
// 312.035 us; speedup vs baseline: 1.0991x; 1.0991x over previous
//
#include <hip/hip_runtime.h>
#include <hip/hip_fp16.h>

#define NNODES 100000
#define NEDGES 3200000
#define FEAT 32
#define NITER 5
#define NF (NNODES * FEAT)

#define EDGE_BLOCKS (NEDGES / 256)     // 12500, exact

// bucket partition
#define BUCK_SH 7
#define BUCK_SZ 128                    // dsts per bucket
#define NBK 782                        // ceil(100000/128)
#define CHUNKF 4096                    // edges per fill/hist block
#define NBF 782                        // ceil(3.2M/4096): 782*4096 = 3,203,072
#define NT (NBF * NBK)                 // 611,524 matrix elements
#define NTB 598                        // ceil(NT/1024)

// ---- pass A: per-edge weight + masked dst array + masked-weight partials ----
__global__ void ws_kernel(const int* __restrict__ edge_index,
                          const int* __restrict__ edge_mask,
                          const float* __restrict__ edge_scale,
                          const float* __restrict__ pert_mask,
                          const float* __restrict__ edge_weight,
                          int* __restrict__ dstm,
                          int* __restrict__ wbuf,
                          float* __restrict__ S_part) {
    const int e = blockIdx.x * 256 + threadIdx.x;   // grid covers NEDGES exactly
    const int m = edge_mask[e];
    const float w = (edge_weight[e] * (1.0f - pert_mask[e]) + pert_mask[e]) * edge_scale[e];
    wbuf[e] = __float_as_int(w);
    dstm[e] = m ? edge_index[NEDGES + e] : -1;
    float ms = m ? 0.0f : w;
    __shared__ float s[256];
    s[threadIdx.x] = ms;
    __syncthreads();
    for (int off = 128; off; off >>= 1) {
        if (threadIdx.x < off) s[threadIdx.x] += s[threadIdx.x + off];
        __syncthreads();
    }
    if (threadIdx.x == 0) S_part[blockIdx.x] = s[0];
}

__global__ void sreduce_kernel(const float* __restrict__ S_part, float* __restrict__ S) {
    __shared__ float s[1024];
    float a = 0.0f;
    for (int i = threadIdx.x; i < EDGE_BLOCKS; i += 1024) a += S_part[i];
    s[threadIdx.x] = a;
    __syncthreads();
    for (int off = 512; off; off >>= 1) {
        if (threadIdx.x < off) s[threadIdx.x] += s[threadIdx.x + off];
        __syncthreads();
    }
    if (threadIdx.x == 0) *S = s[0];
}

// ---- per-(block,bucket) histogram matrix: M[b*NBK + k] ----
__global__ void histmat_kernel(const int* __restrict__ dstm, int* __restrict__ M) {
    __shared__ int h[NBK];
    const int b = blockIdx.x;
    for (int k = threadIdx.x; k < NBK; k += 256) h[k] = 0;
    __syncthreads();
    const int base = b * CHUNKF;
    for (int it = 0; it < CHUNKF / 256; ++it) {
        const int e = base + it * 256 + threadIdx.x;
        if (e < NEDGES) {
            const int d = dstm[e];
            if (d >= 0) atomicAdd(&h[d >> BUCK_SH], 1);
        }
    }
    __syncthreads();
    for (int k = threadIdx.x; k < NBK; k += 256) M[b * NBK + k] = h[k];
}

// ---- 3-stage exclusive scan over M in bucket-major (transposed) order ----
__global__ void tscan1_kernel(const int* __restrict__ M, int* __restrict__ tb) {
    __shared__ int s[1024];
    const int i = blockIdx.x * 1024 + threadIdx.x;
    int v = 0;
    if (i < NT) v = M[(i % NBF) * NBK + (i / NBF)];
    s[threadIdx.x] = v;
    __syncthreads();
    for (int off = 512; off; off >>= 1) {
        if (threadIdx.x < off) s[threadIdx.x] += s[threadIdx.x + off];
        __syncthreads();
    }
    if (threadIdx.x == 0) tb[blockIdx.x] = s[0];
}

__global__ void tscan2_kernel(const int* __restrict__ tb, int* __restrict__ tboff,
                              int* __restrict__ bucket_base) {
    __shared__ int s[1024];
    const int tid = threadIdx.x;
    int v = (tid < NTB) ? tb[tid] : 0;
    s[tid] = v;
    __syncthreads();
    for (int off = 1; off < 1024; off <<= 1) {
        int t = (tid >= off) ? s[tid - off] : 0;
        __syncthreads();
        s[tid] += t;
        __syncthreads();
    }
    if (tid < NTB) tboff[tid] = s[tid] - v;       // exclusive
    if (tid == 1023) bucket_base[NBK] = s[1023];  // total unmasked edges
}

__global__ void tscan3_kernel(const int* __restrict__ M, const int* __restrict__ tboff,
                              int* __restrict__ scanT, int* __restrict__ bucket_base) {
    __shared__ int s[1024];
    const int tid = threadIdx.x;
    const int i = blockIdx.x * 1024 + tid;
    int v = 0;
    if (i < NT) v = M[(i % NBF) * NBK + (i / NBF)];
    s[tid] = v;
    __syncthreads();
    for (int off = 1; off < 1024; off <<= 1) {
        int t = (tid >= off) ? s[tid - off] : 0;
        __syncthreads();
        s[tid] += t;
        __syncthreads();
    }
    if (i < NT) {
        const int excl = tboff[blockIdx.x] + s[tid] - v;
        scanT[i] = excl;
        if (i % NBF == 0) bucket_base[i / NBF] = excl;
    }
}

// ---- fill: scatter (src | dstl<<20, w) to matrix offsets; no global atomics ----
__global__ void fill782_kernel(const int* __restrict__ edge_index,
                               const int* __restrict__ dstm,
                               const int* __restrict__ wbuf,
                               const int* __restrict__ scanT,
                               int2* __restrict__ e8tmp) {
    __shared__ int off[NBK];
    const int b = blockIdx.x;
    for (int k = threadIdx.x; k < NBK; k += 256) off[k] = scanT[k * NBF + b];
    __syncthreads();
    const int base = b * CHUNKF;
    for (int it = 0; it < CHUNKF / 256; ++it) {
        const int e = base + it * 256 + threadIdx.x;
        if (e < NEDGES) {
            const int d = dstm[e];
            if (d >= 0) {
                const int k = d >> BUCK_SH;
                const int dstl = d & (BUCK_SZ - 1);
                const int pos = atomicAdd(&off[k], 1);
                e8tmp[pos] = make_int2(edge_index[e] | (dstl << 20), wbuf[e]);
            }
        }
    }
}

// ---- bucket sort: one block per bucket; LDS counting sort by local dst ----
// emits final dst-sorted e8 (x = fp16-row byte offset, src<<6) and row_ptr
__global__ void bsort_kernel(const int2* __restrict__ e8tmp,
                             const int* __restrict__ bucket_base,
                             int2* __restrict__ e8,
                             int* __restrict__ row_ptr) {
    __shared__ int h[BUCK_SZ];
    __shared__ int s[BUCK_SZ];
    __shared__ int woff[BUCK_SZ];
    const int k = blockIdx.x;
    const int tid = threadIdx.x;
    const int base0 = bucket_base[k];
    const int cnt = bucket_base[k + 1] - base0;
    if (tid < BUCK_SZ) h[tid] = 0;
    __syncthreads();
    for (int i = tid; i < cnt; i += 256) {
        const int dstl = e8tmp[base0 + i].x >> 20;
        atomicAdd(&h[dstl], 1);
    }
    __syncthreads();
    if (tid < BUCK_SZ) s[tid] = h[tid];
    __syncthreads();
    for (int off = 1; off < BUCK_SZ; off <<= 1) {
        int t = 0;
        if (tid < BUCK_SZ && tid >= off) t = s[tid - off];
        __syncthreads();
        if (tid < BUCK_SZ) s[tid] += t;
        __syncthreads();
    }
    if (tid < BUCK_SZ) {
        const int excl = s[tid] - h[tid];
        const int d = k * BUCK_SZ + tid;
        if (d < NNODES) row_ptr[d] = base0 + excl;
        woff[tid] = excl;
    }
    if (k == NBK - 1 && tid == 0) row_ptr[NNODES] = bucket_base[NBK];
    __syncthreads();
    for (int i = tid; i < cnt; i += 256) {
        const int2 v = e8tmp[base0 + i];
        const int dstl = v.x >> 20;
        const int src = v.x & 0xFFFFF;
        const int pos = atomicAdd(&woff[dstl], 1);
        e8[base0 + pos] = make_int2(src << 6, v.y);   // byte offset into fp16 rows (64 B)
    }
}

// ---- initial fp32 -> fp16 conversion of x0 ----
__global__ void cvt_kernel(const float* __restrict__ x, __half* __restrict__ xh) {
    const int i = blockIdx.x * 256 + threadIdx.x;   // i over NF/4
    const float4 v = reinterpret_cast<const float4*>(x)[i];
    __half2* o = reinterpret_cast<__half2*>(xh) + i * 2;
    o[0] = __floats2half2_rn(v.x, v.y);
    o[1] = __floats2half2_rn(v.z, v.w);
}

// ---- gather V2: 16 edges per VMEM instruction ----
// lane l: edge slot (l>>2), feature quarter (l&3) -> 8 feats via one uint4 (16B fp16).
// shfl_xor reduce over the 16 edge slots; 8-lane epilogue does clip + stores.
__global__ void gather_kernel(const float* __restrict__ x,
                              const __half* __restrict__ xh,
                              const int* __restrict__ row_ptr,
                              const int2* __restrict__ e8,
                              const float* __restrict__ S,
                              float* __restrict__ out,
                              __half* __restrict__ outh) {
    const int gid = blockIdx.x * blockDim.x + threadIdx.x;
    const int node = __builtin_amdgcn_readfirstlane(gid >> 6);   // wave-uniform
    const int lane = threadIdx.x & 63;
    const int sub = lane & 3;       // feature quarter
    const int eidx = lane >> 2;     // edge slot 0..15
    const int beg = row_ptr[node];
    const int end = row_ptr[node + 1];

    // preload self term: lanes 0..7 own feats [4l, 4l+4)
    float4 xi4 = make_float4(0.f, 0.f, 0.f, 0.f);
    if (lane < 8) xi4 = *reinterpret_cast<const float4*>(x + node * FEAT + (lane << 2));

    const char* xhc = (const char*)xh;
    float a0 = 0.f, a1 = 0.f, a2 = 0.f, a3 = 0.f, a4 = 0.f, a5 = 0.f, a6 = 0.f, a7 = 0.f;
    const int em1 = end - 1;
    for (int base = beg; base < end; base += 16) {
        const int i = base + eidx;
        const int2 sw = e8[min(i, em1)];
        const float w = (i < end) ? __int_as_float(sw.y) : 0.0f;
        const uint4 hv = *reinterpret_cast<const uint4*>(xhc + ((long)sw.x + (sub << 4)));
        float2 f;
        f = __half22float2(*(const __half2*)&hv.x); a0 = fmaf(w, f.x, a0); a1 = fmaf(w, f.y, a1);
        f = __half22float2(*(const __half2*)&hv.y); a2 = fmaf(w, f.x, a2); a3 = fmaf(w, f.y, a3);
        f = __half22float2(*(const __half2*)&hv.z); a4 = fmaf(w, f.x, a4); a5 = fmaf(w, f.y, a5);
        f = __half22float2(*(const __half2*)&hv.w); a6 = fmaf(w, f.x, a6); a7 = fmaf(w, f.y, a7);
    }
    // reduce across the 16 edge slots (lanes sharing `sub`): xor offsets 4,8,16,32
    #pragma unroll
    for (int off = 4; off < 64; off <<= 1) {
        a0 += __shfl_xor(a0, off); a1 += __shfl_xor(a1, off);
        a2 += __shfl_xor(a2, off); a3 += __shfl_xor(a3, off);
        a4 += __shfl_xor(a4, off); a5 += __shfl_xor(a5, off);
        a6 += __shfl_xor(a6, off); a7 += __shfl_xor(a7, off);
    }
    // redistribute: lane l<8 wants feats [4l,4l+4) = group (l>>1), half (l&1)
    const int g = lane >> 1;
    float v0, v1, v2, v3;
    {
        float lo, hi;
        lo = __shfl(a0, g); hi = __shfl(a4, g); v0 = (lane & 1) ? hi : lo;
        lo = __shfl(a1, g); hi = __shfl(a5, g); v1 = (lane & 1) ? hi : lo;
        lo = __shfl(a2, g); hi = __shfl(a6, g); v2 = (lane & 1) ? hi : lo;
        lo = __shfl(a3, g); hi = __shfl(a7, g); v3 = (lane & 1) ? hi : lo;
    }
    if (lane < 8) {
        if (node == 0) {   // masked-edge bulk contribution (fp32)
            const float S0 = *S;
            v0 = fmaf(S0, xi4.x, v0); v1 = fmaf(S0, xi4.y, v1);
            v2 = fmaf(S0, xi4.z, v2); v3 = fmaf(S0, xi4.w, v3);
        }
        float4 r;
        r.x = fminf(fmaxf(xi4.x + fminf(fmaxf(v0 - xi4.x, -1.f), 1.f), 0.f), 2.f);
        r.y = fminf(fmaxf(xi4.y + fminf(fmaxf(v1 - xi4.y, -1.f), 1.f), 0.f), 2.f);
        r.z = fminf(fmaxf(xi4.z + fminf(fmaxf(v2 - xi4.z, -1.f), 1.f), 0.f), 2.f);
        r.w = fminf(fmaxf(xi4.w + fminf(fmaxf(v3 - xi4.w, -1.f), 1.f), 0.f), 2.f);
        *reinterpret_cast<float4*>(out + node * FEAT + (lane << 2)) = r;
        __half2 h01 = __floats2half2_rn(r.x, r.y);
        __half2 h23 = __floats2half2_rn(r.z, r.w);
        uint2 hh = make_uint2(*(unsigned*)&h01, *(unsigned*)&h23);
        *reinterpret_cast<uint2*>((char*)outh + ((long)node << 6) + (lane << 3)) = hh;
    }
}

extern "C" void kernel_launch(void* const* d_in, const int* in_sizes, int n_in,
                              void* d_out, int out_size, void* d_ws, size_t ws_size,
                              hipStream_t stream) {
    const float* x0         = (const float*)d_in[0];
    const int*   edge_index = (const int*)d_in[1];
    const int*   edge_mask  = (const int*)d_in[2];
    const float* edge_scale = (const float*)d_in[3];
    const float* pert_mask  = (const float*)d_in[4];
    const float* edge_weight= (const float*)d_in[5];
    float* xout = (float*)d_out;

    // ---- workspace layout (time-multiplexed; ordering noted) ----
    // [0, 80K)      scalars / scan partials
    // [80K, 480K)   row_ptr
    // [1M, 3.45M)   M (611,524 ints)
    // [4M, 6.45M)   scanT  -- OVERLAPS x_mid head; scanT last read in fill782,
    //               x_mid first written in gather it=1 (after bsort) -> safe
    // [4M, 16.8M)   x_mid (fp32)
    // [17M, 29.8M)  e8tmp (dead after bsort)
    // [30M, 42.8M)  e8 (live all gathers)
    // [43M, 55.8M)  wbuf (dead after fill782)  -> xh0 [43M, 49.4M), xh1 [50M, 56.4M)
    // [56M, 68.8M)  dstm (dead after fill782)  -> xh1 tail overlaps safely
    char* ws = (char*)d_ws;
    float* S        = (float*)(ws);                          // 4 B
    float* S_part   = (float*)(ws + 1024);                   // 12500 floats
    int*   tb       = (int*)(ws + 64 * 1024);                // 598 ints
    int*   tboff    = (int*)(ws + 68 * 1024);                // 598 ints
    int*   bbase    = (int*)(ws + 72 * 1024);                // 783 ints
    int*   row_ptr  = (int*)(ws + 80 * 1024);                // 100001 ints
    int*   M        = (int*)(ws + 1024 * 1024);              // NT ints (2.45 MB)
    int*   scanT    = (int*)(ws + 4  * 1024 * 1024);         // NT ints (2.45 MB)
    float* x_mid    = (float*)(ws + 4  * 1024 * 1024);       // 12.8 MB (see note)
    int2*  e8tmp    = (int2*)(ws + 17 * 1024 * 1024);        // 12.8 MB
    int2*  e8       = (int2*)(ws + 30 * 1024 * 1024);        // 12.8 MB
    int*   wbuf     = (int*)(ws + 43 * 1024 * 1024);         // 12.8 MB
    int*   dstm     = (int*)(ws + 56 * 1024 * 1024);         // 12.8 MB
    __half* xh0     = (__half*)(ws + 43 * 1024 * 1024);      // 6.4 MB, aliases dead wbuf
    __half* xh1     = (__half*)(ws + 50 * 1024 * 1024);      // 6.4 MB, aliases dead wbuf/dstm

    ws_kernel<<<EDGE_BLOCKS, 256, 0, stream>>>(edge_index, edge_mask, edge_scale,
                                               pert_mask, edge_weight, dstm, wbuf, S_part);
    sreduce_kernel<<<1, 1024, 0, stream>>>(S_part, S);
    histmat_kernel<<<NBF, 256, 0, stream>>>(dstm, M);
    tscan1_kernel<<<NTB, 1024, 0, stream>>>(M, tb);
    tscan2_kernel<<<1, 1024, 0, stream>>>(tb, tboff, bbase);
    tscan3_kernel<<<NTB, 1024, 0, stream>>>(M, tboff, scanT, bbase);
    fill782_kernel<<<NBF, 256, 0, stream>>>(edge_index, dstm, wbuf, scanT, e8tmp);
    bsort_kernel<<<NBK, 256, 0, stream>>>(e8tmp, bbase, e8, row_ptr);
    cvt_kernel<<<NF / 4 / 256, 256, 0, stream>>>(x0, xh0);   // 3125 blocks, exact

    // 5 gather iterations, ping-pong: x0 -> out -> mid -> out -> mid -> out
    const int gblocks = (NNODES * 64) / 256;   // 25000, exact
    const float* cur = x0;
    float* bufs[NITER] = { xout, x_mid, xout, x_mid, xout };
    __half* xhb[2] = { xh0, xh1 };
    for (int it = 0; it < NITER; ++it) {
        gather_kernel<<<gblocks, 256, 0, stream>>>(cur, xhb[it & 1], row_ptr, e8, S,
                                                   bufs[it], xhb[(it + 1) & 1]);
        cur = bufs[it];
    }
}